// Round 1
// baseline (65.109 us; speedup 1.0000x reference)
//
#include <hip/hip_runtime.h>
#include <math.h>

#define BATCH 256
#define NF 512
#define NQ 16
#define NC 10

// Closed-form collapse of the product-state quantum circuit:
//   exp_vals[b,q] = cos(encoded[b,15-q]) * cos(sum_d theta[d*16 + (15-q)])
//   logits = exp_vals @ cls_w^T + cls_b
__global__ __launch_bounds__(256) void hybrid_fcl_kernel(
    const float* __restrict__ x,      // (256,512)
    const float* __restrict__ enc_w,  // (16,512)
    const float* __restrict__ enc_b,  // (16,)
    const float* __restrict__ theta,  // (64,)
    const float* __restrict__ cls_w,  // (10,16)
    const float* __restrict__ cls_b,  // (10,)
    float* __restrict__ out)          // (256,10)
{
    __shared__ float s_x[NF];
    __shared__ float s_ev[NQ];

    const int b = blockIdx.x;
    const int t = threadIdx.x;

    // stage x row (512 floats) into LDS, coalesced
    s_x[t]       = x[b * NF + t];
    s_x[t + 256] = x[b * NF + t + 256];
    __syncthreads();

    const int wave = t >> 6;   // 0..3
    const int lane = t & 63;

    // each wave computes 4 encoding dots (qubit kron-positions p)
    #pragma unroll
    for (int k = 0; k < 4; ++k) {
        const int p = wave * 4 + k;
        const float* __restrict__ wrow = enc_w + p * NF;
        float acc = 0.f;
        #pragma unroll
        for (int j = 0; j < 8; ++j) {
            const int i = lane + 64 * j;   // coalesced across the wave
            acc += s_x[i] * wrow[i];
        }
        // wave-64 shuffle reduction
        #pragma unroll
        for (int off = 32; off > 0; off >>= 1)
            acc += __shfl_down(acc, off, 64);
        if (lane == 0) {
            const float ang = acc + enc_b[p];
            const float th  = theta[p] + theta[p + 16] + theta[p + 32] + theta[p + 48];
            // bit-index q = 15 - kron-position p
            s_ev[NQ - 1 - p] = __cosf(ang) * cosf(th);
        }
    }
    __syncthreads();

    // classifier: 10 outputs, 16-dot each
    if (t < NC) {
        float acc = cls_b[t];
        #pragma unroll
        for (int q = 0; q < NQ; ++q)
            acc += s_ev[q] * cls_w[t * NQ + q];
        out[b * NC + t] = acc;
    }
}

extern "C" void kernel_launch(void* const* d_in, const int* in_sizes, int n_in,
                              void* d_out, int out_size, void* d_ws, size_t ws_size,
                              hipStream_t stream) {
    const float* x     = (const float*)d_in[0];
    const float* enc_w = (const float*)d_in[1];
    const float* enc_b = (const float*)d_in[2];
    const float* theta = (const float*)d_in[3];
    const float* cls_w = (const float*)d_in[4];
    const float* cls_b = (const float*)d_in[5];
    float* out = (float*)d_out;

    hybrid_fcl_kernel<<<BATCH, 256, 0, stream>>>(x, enc_w, enc_b, theta, cls_w, cls_b, out);
}

// Round 2
// 63.493 us; speedup vs baseline: 1.0255x; 1.0255x over previous
//
#include <hip/hip_runtime.h>
#include <math.h>

#define BATCH 256
#define NF 512
#define NQ 16
#define NC 10

// Closed-form collapse of the product-state quantum circuit (no entangling
// gates -> product state):
//   exp_vals[b,q] = cos(encoded[b,15-q]) * cos(sum_d theta[d*16 + (15-q)])
//   logits = exp_vals @ cls_w^T + cls_b
//
// Layout: 1 block per batch row, 256 threads = 4 waves.
// Each wave handles 4 qubits CONCURRENTLY: 16 lanes per qubit, 32 elems/lane,
// 4-step width-16 shuffle reduce (short dependent chain, latency-bound regime).
__global__ __launch_bounds__(256) void hybrid_fcl_kernel(
    const float* __restrict__ x,      // (256,512)
    const float* __restrict__ enc_w,  // (16,512)
    const float* __restrict__ enc_b,  // (16,)
    const float* __restrict__ theta,  // (64,)
    const float* __restrict__ cls_w,  // (10,16)
    const float* __restrict__ cls_b,  // (10,)
    float* __restrict__ out)          // (256,10)
{
    __shared__ float s_x[NF];
    __shared__ float s_ev[NQ];

    const int b = blockIdx.x;
    const int t = threadIdx.x;

    // stage x row (512 floats) into LDS, coalesced
    s_x[t]       = x[b * NF + t];
    s_x[t + 256] = x[b * NF + t + 256];
    __syncthreads();

    const int wave = t >> 6;       // 0..3
    const int lane = t & 63;
    const int g    = lane >> 4;    // qubit sub-group within wave: 0..3
    const int s    = lane & 15;    // lane within sub-group
    const int p    = wave * 4 + g; // qubit kron-position 0..15

    const float* __restrict__ wrow = enc_w + p * NF;

    // 512-dot: 32 elements per lane, two independent accumulators
    float a0 = 0.f, a1 = 0.f;
    #pragma unroll
    for (int j = 0; j < 16; ++j) {
        const int i0 = s + 16 * (2 * j);
        const int i1 = s + 16 * (2 * j + 1);
        a0 += s_x[i0] * wrow[i0];
        a1 += s_x[i1] * wrow[i1];
    }
    float acc = a0 + a1;

    // reduce across the 16 lanes of this sub-group
    acc += __shfl_down(acc, 8, 16);
    acc += __shfl_down(acc, 4, 16);
    acc += __shfl_down(acc, 2, 16);
    acc += __shfl_down(acc, 1, 16);

    if (s == 0) {
        const float ang = acc + enc_b[p];
        const float th  = theta[p] + theta[p + 16] + theta[p + 32] + theta[p + 48];
        // bit-index q = 15 - kron-position p
        s_ev[NQ - 1 - p] = __cosf(ang) * __cosf(th);
    }
    __syncthreads();

    // classifier: 10 outputs, 16-dot each
    if (t < NC) {
        float acc2 = cls_b[t];
        #pragma unroll
        for (int q = 0; q < NQ; ++q)
            acc2 += s_ev[q] * cls_w[t * NQ + q];
        out[b * NC + t] = acc2;
    }
}

extern "C" void kernel_launch(void* const* d_in, const int* in_sizes, int n_in,
                              void* d_out, int out_size, void* d_ws, size_t ws_size,
                              hipStream_t stream) {
    const float* x     = (const float*)d_in[0];
    const float* enc_w = (const float*)d_in[1];
    const float* enc_b = (const float*)d_in[2];
    const float* theta = (const float*)d_in[3];
    const float* cls_w = (const float*)d_in[4];
    const float* cls_b = (const float*)d_in[5];
    float* out = (float*)d_out;

    hybrid_fcl_kernel<<<BATCH, 256, 0, stream>>>(x, enc_w, enc_b, theta, cls_w, cls_b, out);
}